// Round 1
// 840.379 us; speedup vs baseline: 1.2722x; 1.2722x over previous
//
#include <hip/hip_runtime.h>
#include <math.h>

#define HW25600 25600
#define DIM 128
#define NPIX 409600
#define KCAND 100
#define RPAD 128
#define DSW 3200              // u32 words per downsampled row-mask (320*320 bits)
#define MOUT 40960000         // masks output elements (100*640*640)
#define NBLK 3200             // gemm blocks (one per 128-px tile)

// ---- workspace byte offsets ----
#define WS_TOPV    0          // f32[128] top_s
#define WS_TOPI    512        // i32[128] indices
#define WS_VALID   1024       // f32[128]
#define WS_KEEPF   1536       // f32[128]
#define WS_MNT     2048       // f32[128*128] mn, layout [d][r]
#define WS_META    67584      // f32[128*128] meta, layout [r][d]
#define WS_CNT     133120     // f64[128] seg pixel counts
#define WS_SSUM    134144     // f64[128] seg score sums
#define WS_INTER   135168     // f32[100*100] downsampled mask intersections
#define WS_APREP1  175168     // 64KB: pre-split/pre-swizzled bf16 hi/lo A (pre-NMS order)
#define WS_SCALE2  240704     // f32[128] final row scales (keep2)
#define WS_DS      241216     // u32[128*3200] bitpacked downsampled masks
#define WS_PART    1879616    // f32[3200*256] per-block stat partials (cnt|ssum)
#define WS_APREP2  1879616    // 64KB: post-NMS A prep; aliases part (dead after stats_reduce)
// total: 5,156,416 bytes (unchanged)

typedef short  s16x8  __attribute__((ext_vector_type(8)));
typedef float  f32x16 __attribute__((ext_vector_type(16)));

// even-bit compress: bit 2j -> bit j (inverse of morton spread)
__device__ __forceinline__ unsigned int compact16(unsigned int x) {
  x &= 0x55555555u;
  x = (x | (x >> 1)) & 0x33333333u;
  x = (x | (x >> 2)) & 0x0F0F0F0Fu;
  x = (x | (x >> 4)) & 0x00FF00FFu;
  x = (x | (x >> 8)) & 0x0000FFFFu;
  return x;
}

// Split A (fp32, [k][RPAD] layout) into bf16 hi/lo, writing the PRE-SWIZZLED
// global image of the gemm's LDS tile so staging is a linear 16B copy
// (global_load-friendly) and fragment ds_read_b128 is bank-minimal.
// dst layout: [c(2)][hl(2)][r(128)][u(8)] 16B units; unit (c,r,u) holds
// A[r][ c*64 + (u^(r&7))*8 + e ], e=0..7.
__device__ __forceinline__ void prep_a(const float* __restrict__ srcKR,
                                       const int* order,
                                       char* __restrict__ dst, int tid) {
  for (int t = tid; t < 2048; t += 256) {
    int r = t >> 4;
    int c = (t >> 3) & 1;
    int u = t & 7;
    int rs = r;
    bool zero = false;
    if (order) { if (r < KCAND) rs = order[r]; else zero = true; }
    union { s16x8 v; short s[8]; } H, L;
    #pragma unroll
    for (int e = 0; e < 8; ++e) {
      int k = c * 64 + ((u ^ (r & 7)) << 3) + e;
      float x = zero ? 0.0f : srcKR[k * RPAD + rs];
      unsigned int ux = __float_as_uint(x);
      unsigned int hb = ux & 0xFFFF0000u;          // truncate-to-bf16 (hi)
      float lo = x - __uint_as_float(hb);          // exact residual
      H.s[e] = (short)(hb >> 16);
      L.s[e] = (short)(__float_as_uint(lo) >> 16); // truncate-to-bf16 (lo)
    }
    *(s16x8*)(dst + c * 32768 + r * 128 + u * 16) = H.v;
    *(s16x8*)(dst + c * 32768 + 16384 + r * 128 + u * 16) = L.v;
  }
}

// ============ kernel 1: sigmoid + top-100 (radix histogram select) ============
__global__ __launch_bounds__(256) void topk_kernel(const float* __restrict__ pred, char* ws) {
  float* topv   = (float*)(ws + WS_TOPV);
  int*   topi   = (int*)(ws + WS_TOPI);
  float* validf = (float*)(ws + WS_VALID);

  __shared__ unsigned int hist[1024];
  __shared__ float cv[1024];
  __shared__ int ci[1024];
  __shared__ int scl[4];
  __shared__ unsigned int ncand;

  int tid = threadIdx.x;
  for (int b = tid; b < 1024; b += 256) hist[b] = 0;
  if (tid == 0) ncand = 0;
  __syncthreads();

  for (int k = tid; k < HW25600; k += 256) {
    float s = 1.0f / (1.0f + expf(-pred[k]));
    unsigned int u = __float_as_uint(s);
    atomicAdd(&hist[u >> 21], 1u);
  }
  __syncthreads();
  if (tid == 0) {
    int c = 0, B = 0;
    for (int b = 1023; b >= 0; --b) {
      int h = (int)hist[b];
      if (c + h >= KCAND) { B = b; break; }
      c += h;
    }
    scl[0] = B; scl[1] = c;
  }
  __syncthreads();
  int B = scl[0], cAb = scl[1];
  __syncthreads();
  for (int b = tid; b < 1024; b += 256) hist[b] = 0;
  __syncthreads();
  for (int k = tid; k < HW25600; k += 256) {
    float s = 1.0f / (1.0f + expf(-pred[k]));
    unsigned int u = __float_as_uint(s);
    if ((int)(u >> 21) == B) atomicAdd(&hist[(u >> 11) & 1023], 1u);
  }
  __syncthreads();
  if (tid == 0) {
    int target = KCAND - cAb;
    int c = 0, B2 = 0;
    for (int b = 1023; b >= 0; --b) {
      int h = (int)hist[b];
      if (c + h >= target) { B2 = b; break; }
      c += h;
    }
    scl[2] = B2;
  }
  __syncthreads();
  unsigned int thr = ((unsigned int)B << 21) | ((unsigned int)scl[2] << 11);
  for (int k = tid; k < HW25600; k += 256) {
    float s = 1.0f / (1.0f + expf(-pred[k]));
    unsigned int u = __float_as_uint(s);
    if (u >= thr) {
      unsigned int slot = atomicAdd(&ncand, 1u);
      if (slot < 1024u) { cv[slot] = s; ci[slot] = k; }
    }
  }
  __syncthreads();
  int nc = (int)(ncand < 1024u ? ncand : 1024u);
  for (int c = tid; c < nc; c += 256) {
    float v = cv[c]; int id = ci[c];
    int rk = 0;
    for (int o = 0; o < nc; ++o) {
      float u2 = cv[o]; int i2 = ci[o];
      rk += (int)((u2 > v) || (u2 == v && i2 < id));
    }
    if (rk < KCAND) {
      topv[rk] = v; topi[rk] = id;
      validf[rk] = (v > 0.75f) ? 1.0f : 0.0f;
    }
  }
  for (int r = tid; r < RPAD; r += 256)
    if (r >= KCAND) { topv[r] = 0.0f; topi[r] = 0; validf[r] = 0.0f; }
}

// ============ kernel 2: feat gather, cosine sim, dedup, meta kernels, mn + A-prep ============
__global__ __launch_bounds__(256) void fuse_kernel(const float* __restrict__ emb, char* ws) {
  int*   topi   = (int*)(ws + WS_TOPI);
  float* validfg= (float*)(ws + WS_VALID);
  float* keepfg = (float*)(ws + WS_KEEPF);
  float* mnt    = (float*)(ws + WS_MNT);
  float* metag  = (float*)(ws + WS_META);

  __shared__ float feat_s[KCAND * DIM];
  __shared__ unsigned int lab[KCAND * 4];
  __shared__ unsigned int lkb[KCAND * 4];
  __shared__ float rinv[KCAND];
  __shared__ float valids[KCAND];
  __shared__ float keeps[KCAND];
  __shared__ float divis[KCAND];
  __shared__ float mnrm[KCAND];

  int tid = threadIdx.x;
  for (int t = tid; t < KCAND * 4; t += 256) { lab[t] = 0u; lkb[t] = 0u; }
  for (int i = tid; i < KCAND; i += 256) valids[i] = validfg[i];
  for (int t = tid; t < KCAND * DIM; t += 256) {
    int i = t >> 7, d = t & 127;
    feat_s[t] = emb[d * HW25600 + topi[i]];
  }
  __syncthreads();
  for (int i = tid; i < KCAND; i += 256) {
    float n2 = 0.0f;
    for (int d = 0; d < DIM; ++d) { float f = feat_s[i*DIM+d]; n2 = fmaf(f, f, n2); }
    rinv[i] = 1.0f / fmaxf(sqrtf(n2), 1e-8f);
  }
  __syncthreads();
  for (int t = tid; t < KCAND*KCAND; t += 256) {
    int i = t / KCAND, j = t - i*KCAND;
    if (i <= j && valids[i] > 0.0f && valids[j] > 0.0f) {
      float dp = 0.0f;
      for (int d = 0; d < DIM; ++d) dp = fmaf(feat_s[i*DIM+d], feat_s[j*DIM+d], dp);
      float sim = dp * rinv[i] * rinv[j];
      if (sim >= 0.75f) atomicOr(&lab[i*4 + (j>>5)], 1u << (j & 31));
    }
  }
  __syncthreads();
  for (int j = tid; j < KCAND; j += 256) {
    int c = 0;
    for (int i = 0; i < KCAND; ++i) {
      unsigned int l = (lab[i*4 + (j>>5)] >> (j & 31)) & 1u;
      c += (int)l;
      if (l && c < 2) atomicOr(&lkb[i*4 + (j>>5)], 1u << (j & 31));
      if (i == j) keeps[j] = (c < 2 && valids[j] > 0.0f) ? 1.0f : 0.0f;
    }
  }
  __syncthreads();
  for (int i = tid; i < KCAND; i += 256) {
    int cnt = 0;
    for (int w = 0; w < 4; ++w) cnt += __popc(lkb[i*4+w]);
    divis[i] = fmaxf((keeps[i] > 0.0f) ? (float)cnt : 0.0f, 1.0f);
  }
  __syncthreads();
  for (int t = tid; t < KCAND*DIM; t += 256) {
    int i = t >> 7, d = t & 127;
    float s = 0.0f;
    if (keeps[i] > 0.0f) {
      for (int w = 0; w < 4; ++w) {
        unsigned int m = lkb[i*4+w];
        while (m) {
          int j = (w << 5) + __ffs(m) - 1;
          m &= m - 1u;
          s += feat_s[j*DIM + d];
        }
      }
    }
    metag[t] = s / divis[i];
  }
  __syncthreads();
  for (int i = tid; i < KCAND; i += 256) {
    float n2 = 0.0f;
    for (int d = 0; d < DIM; ++d) { float f = metag[i*DIM+d]; n2 = fmaf(f, f, n2); }
    mnrm[i] = fmaxf(sqrtf(n2), 1e-8f);
  }
  __syncthreads();
  // mn transposed [d][r], rows 100..127 zero-padded
  for (int t = tid; t < RPAD*DIM; t += 256) {
    int d = t >> 7, r = t & 127;
    float v = 0.0f;
    if (r < KCAND) v = metag[r*DIM + d] / mnrm[r];
    mnt[d*RPAD + r] = v;
  }
  for (int r = tid; r < RPAD; r += 256) keepfg[r] = (r < KCAND) ? keeps[r] : 0.0f;
  __syncthreads();
  // split/swizzle A for the MFMA gemm (pre-NMS row order)
  prep_a(mnt, (const int*)0, ws + WS_APREP1, tid);
}

// ============ kernel 3/7: MFMA GEMM sigmoid(mn @ enc) via split-bf16 ============
// Block = 128-px tile, 4 waves; wave w owns px [bx*128 + w*32, +32).
// Per wave: 4 row-tiles (m) x 8 k-steps x 3 products of mfma_f32_32x32x16_bf16.
// A (mn hi/lo) staged per 64-k chunk from pre-swizzled global (32KB LDS, linear copy).
// B (enc) loaded straight into fragments (8 x dword, 2x128B segments/instr) and
// hi/lo-split in registers with bit-ops only.
template<bool STATS>
__global__ __launch_bounds__(256, 3) void gemm_kernel(const float* __restrict__ enc,
                                                      char* __restrict__ ws,
                                                      float* __restrict__ out) {
  __shared__ __align__(16) short alds[16384];   // 32KB: [hl][r(128)][u(8)] 16B units
  __shared__ float scale_s[RPAD];
  __shared__ float red_s[2][RPAD][4];           // stats partials per wave
  __shared__ unsigned int dsw_s[RPAD][2];       // ds bitmask words per block

  const char*  aprep = ws + (STATS ? WS_APREP1 : WS_APREP2);
  const float* ssrc  = (const float*)(ws + (STATS ? WS_KEEPF : WS_SCALE2));

  int tid  = threadIdx.x;
  int lane = tid & 63;
  int w    = tid >> 6;       // wave 0..3
  int cl   = lane & 31;      // MFMA column (px) / A row within tile
  int hgrp = lane >> 5;      // k-subgroup of 8
  int bx   = blockIdx.x;
  int px   = bx * 128 + w * 32 + cl;

  if (tid < RPAD) scale_s[tid] = ssrc[tid];
  if (STATS) dsw_s[tid >> 1][tid & 1] = 0u;

  f32x16 acc[4];
  #pragma unroll
  for (int mt = 0; mt < 4; ++mt) acc[mt] = (f32x16)0.0f;

  const float4* asrc = (const float4*)aprep;
  for (int c = 0; c < 2; ++c) {
    __syncthreads();                       // protect alds reuse
    #pragma unroll
    for (int i = 0; i < 8; ++i)
      ((float4*)alds)[tid + 256 * i] = asrc[c * 2048 + tid + 256 * i];
    __syncthreads();

    const float* ep = enc + (size_t)(c * 64 + hgrp * 8) * NPIX + px;
    #pragma unroll
    for (int ks = 0; ks < 4; ++ks) {
      // B fragment: k = c*64 + ks*16 + hgrp*8 + i
      float bv[8];
      #pragma unroll
      for (int i = 0; i < 8; ++i) bv[i] = ep[(size_t)(ks * 16 + i) * NPIX];
      union { s16x8 v; unsigned int u[4]; } Bh, Bl;
      #pragma unroll
      for (int i = 0; i < 4; ++i) {
        unsigned int u0 = __float_as_uint(bv[2*i]);
        unsigned int u1 = __float_as_uint(bv[2*i+1]);
        unsigned int h0 = u0 & 0xFFFF0000u, h1 = u1 & 0xFFFF0000u;
        float l0 = bv[2*i]   - __uint_as_float(h0);
        float l1 = bv[2*i+1] - __uint_as_float(h1);
        Bh.u[i] = (h0 >> 16) | h1;
        Bl.u[i] = (__float_as_uint(l0) >> 16) | (__float_as_uint(l1) & 0xFFFF0000u);
      }
      // A fragments (hi+lo) for 4 row-tiles; swizzled unit index
      s16x8 ah[4], al[4];
      #pragma unroll
      for (int mt = 0; mt < 4; ++mt) {
        int r = mt * 32 + cl;
        int u = (ks * 2 + hgrp) ^ (r & 7);
        const short* ap = alds + r * 64 + u * 8;
        ah[mt] = *(const s16x8*)ap;
        al[mt] = *(const s16x8*)(ap + 8192);
      }
      // 3-product split accumulation; consecutive MFMAs hit different acc regs
      #pragma unroll
      for (int mt = 0; mt < 4; ++mt)
        acc[mt] = __builtin_amdgcn_mfma_f32_32x32x16_bf16(ah[mt], Bh.v, acc[mt], 0, 0, 0);
      #pragma unroll
      for (int mt = 0; mt < 4; ++mt)
        acc[mt] = __builtin_amdgcn_mfma_f32_32x32x16_bf16(ah[mt], Bl.v, acc[mt], 0, 0, 0);
      #pragma unroll
      for (int mt = 0; mt < 4; ++mt)
        acc[mt] = __builtin_amdgcn_mfma_f32_32x32x16_bf16(al[mt], Bh.v, acc[mt], 0, 0, 0);
    }
  }

  // D layout (verified): col = lane&31 (= our px), row = (q&3) + 8*(q>>2) + 4*hgrp
  int y = bx / 5, xw = bx - y * 5;
  bool yeven = (y & 1) == 0;
  if (STATS) {
    #pragma unroll
    for (int mt = 0; mt < 4; ++mt) {
      #pragma unroll
      for (int q = 0; q < 16; ++q) {
        int r = mt * 32 + (q & 3) + 8 * (q >> 2) + 4 * hgrp;
        float s = scale_s[r] * (1.0f / (1.0f + expf(-acc[mt][q])));
        bool bb = s > 0.45f;
        unsigned long long bm = __ballot(bb);
        unsigned int hbits = (unsigned int)(bm >> (hgrp * 32));
        float ssum = bb ? s : 0.0f;
        #pragma unroll
        for (int off = 1; off <= 16; off <<= 1) ssum += __shfl_xor(ssum, off);
        if ((lane & 31) == 0) {
          red_s[0][r][w] = (float)__popc(hbits);
          red_s[1][r][w] = ssum;
        }
        if (yeven) {
          unsigned int ex = compact16(hbits);   // even-x bits of this wave's 32 px
          if ((lane & 31) == 0)
            atomicOr(&dsw_s[r][w >> 1], ex << ((w & 1) * 16));
        }
      }
    }
    __syncthreads();
    float* part = (float*)(ws + WS_PART);
    unsigned int* ds32 = (unsigned int*)(ws + WS_DS);
    int r = tid & 127, st = tid >> 7;
    part[bx * 256 + st * 128 + r] =
        red_s[st][r][0] + red_s[st][r][1] + red_s[st][r][2] + red_s[st][r][3];
    if (yeven) {
      int rr = tid >> 1, wd = tid & 1;
      ds32[rr * DSW + (y >> 1) * 10 + xw * 2 + wd] = dsw_s[rr][wd];
    }
  } else {
    #pragma unroll
    for (int mt = 0; mt < 4; ++mt) {
      #pragma unroll
      for (int q = 0; q < 16; ++q) {
        int r = mt * 32 + (q & 3) + 8 * (q >> 2) + 4 * hgrp;
        if (r < KCAND) {
          float o = scale_s[r] * (1.0f / (1.0f + expf(-acc[mt][q])));
          out[(size_t)r * NPIX + px] = o;
        }
      }
    }
  }
}

// ============ kernel 4: deterministic f64 reduce of per-block stat partials ============
__global__ __launch_bounds__(256) void stats_reduce_kernel(char* ws) {
  const float* part = (const float*)(ws + WS_PART);
  double* cntd  = (double*)(ws + WS_CNT);
  double* ssumd = (double*)(ws + WS_SSUM);
  __shared__ double cs_[256], ss_[256];
  int tid = threadIdx.x;
  int r = blockIdx.x;
  double c = 0.0, s = 0.0;
  for (int b = tid; b < NBLK; b += 256) {
    c += (double)part[b * 256 + r];
    s += (double)part[b * 256 + RPAD + r];
  }
  cs_[tid] = c; ss_[tid] = s;
  __syncthreads();
  for (int o = 128; o >= 1; o >>= 1) {
    if (tid < o) { cs_[tid] += cs_[tid + o]; ss_[tid] += ss_[tid + o]; }
    __syncthreads();
  }
  if (tid == 0) { cntd[r] = cs_[0]; ssumd[r] = ss_[0]; }
}

// ============ kernel 5: pairwise mask intersections (popcount over bitpacked ds) ============
__global__ __launch_bounds__(256) void inter_kernel(char* ws) {
  int i = blockIdx.y, j = blockIdx.x;
  if (j < i) return;
  const unsigned int* ds32 = (const unsigned int*)(ws + WS_DS);
  float* inter = (float*)(ws + WS_INTER);
  const unsigned int* a = ds32 + i * DSW;
  const unsigned int* b = ds32 + j * DSW;
  int s = 0;
  for (int w = threadIdx.x; w < DSW; w += 256) s += __popc(a[w] & b[w]);
  #pragma unroll
  for (int off = 32; off >= 1; off >>= 1) s += __shfl_xor(s, off);
  __shared__ int red[4];
  int lane = threadIdx.x & 63, wv = threadIdx.x >> 6;
  if (lane == 0) red[wv] = s;
  __syncthreads();
  if (threadIdx.x == 0) inter[i*KCAND + j] = (float)(red[0] + red[1] + red[2] + red[3]);
}

// ============ kernel 6: score/sort/matrix-NMS, small outputs, build A2/scale2 ============
__global__ __launch_bounds__(256) void nms_kernel(char* ws, float* __restrict__ out) {
  float* topv   = (float*)(ws + WS_TOPV);
  float* keepfg = (float*)(ws + WS_KEEPF);
  double* cntd  = (double*)(ws + WS_CNT);
  double* ssumd = (double*)(ws + WS_SSUM);
  float* inter  = (float*)(ws + WS_INTER);
  float* mnt    = (float*)(ws + WS_MNT);
  float* scale2 = (float*)(ws + WS_SCALE2);

  __shared__ float iou_s[KCAND*KCAND];   // 40 KB
  __shared__ float sc0[KCAND], sc_s[KCAND], keep_s[KCAND], s2_s[KCAND];
  __shared__ float comp_[KCAND], k2f_[KCAND];
  __shared__ int order_[KCAND];

  int tid = threadIdx.x;
  for (int r = tid; r < KCAND; r += 256) {
    double c = cntd[r], s = ssumd[r];
    float seg = (float)(s / fmax(c, 1.0));
    sc0[r] = topv[r] * seg;
  }
  __syncthreads();
  for (int i = tid; i < KCAND; i += 256) {
    float v = sc0[i]; int rk = 0;
    for (int j = 0; j < KCAND; ++j) {
      float u = sc0[j];
      rk += (int)((u > v) || (u == v && j < i));
    }
    order_[rk] = i;
  }
  __syncthreads();
  for (int i = tid; i < KCAND; i += 256) {
    int oi = order_[i];
    sc_s[i]   = sc0[oi];
    keep_s[i] = keepfg[oi];
    s2_s[i]   = inter[oi*KCAND + oi];
  }
  __syncthreads();
  for (int t = tid; t < KCAND*KCAND; t += 256) {
    int i = t / KCAND, j = t - i*KCAND;
    float v = 0.0f;
    if (i < j) {
      int oi = order_[i], oj = order_[j];
      int a = min(oi, oj), b = max(oi, oj);
      float iv = inter[a*KCAND + b];
      float un = s2_s[i] + s2_s[j] - iv;
      v = iv / fmaxf(un, 1e-6f);
    }
    iou_s[t] = v;
  }
  __syncthreads();
  for (int i = tid; i < KCAND; i += 256) {
    float m = 0.0f;
    for (int r = 0; r < KCAND; ++r) m = fmaxf(m, iou_s[r*KCAND + i]);
    comp_[i] = m;
  }
  __syncthreads();
  for (int j = tid; j < KCAND; j += 256) {
    float mv = 3.4e38f;
    for (int i = 0; i < KCAND; ++i) {
      float io = iou_s[i*KCAND + j];
      float cm = comp_[i];
      float ratio = expf(-2.0f*io*io) / expf(-2.0f*cm*cm);
      mv = fminf(mv, ratio);
    }
    float sc2 = sc_s[j] * mv;
    bool k2 = (sc2 >= 0.05f) && (keep_s[j] > 0.5f);
    float kf = k2 ? 1.0f : 0.0f;
    k2f_[j] = kf;
    out[MOUT + j] = sc2 * kf;                 // scores
    out[MOUT + KCAND + j] = 0.0f;             // labels
    out[MOUT + 2*KCAND + j] = kf;             // keep
  }
  __syncthreads();
  // split/swizzle permuted A for the final MFMA gemm (replaces mn2t)
  prep_a(mnt, order_, ws + WS_APREP2, tid);
  for (int r = tid; r < RPAD; r += 256) scale2[r] = (r < KCAND) ? k2f_[r] : 0.0f;
}

extern "C" void kernel_launch(void* const* d_in, const int* in_sizes, int n_in,
                              void* d_out, int out_size, void* d_ws, size_t ws_size,
                              hipStream_t stream) {
  const float* pred = (const float*)d_in[0];
  const float* emb  = (const float*)d_in[1];
  const float* enc  = (const float*)d_in[2];
  float* out = (float*)d_out;
  char* ws = (char*)d_ws;

  topk_kernel<<<dim3(1), dim3(256), 0, stream>>>(pred, ws);
  fuse_kernel<<<dim3(1), dim3(256), 0, stream>>>(emb, ws);
  gemm_kernel<true><<<dim3(NBLK), dim3(256), 0, stream>>>(enc, ws, out);
  stats_reduce_kernel<<<dim3(RPAD), dim3(256), 0, stream>>>(ws);
  inter_kernel<<<dim3(100, 100), dim3(256), 0, stream>>>(ws);
  nms_kernel<<<dim3(1), dim3(256), 0, stream>>>(ws, out);
  gemm_kernel<false><<<dim3(NBLK), dim3(256), 0, stream>>>(enc, ws, out);
}

// Round 2
// 806.382 us; speedup vs baseline: 1.3258x; 1.0422x over previous
//
#include <hip/hip_runtime.h>
#include <math.h>

#define HW25600 25600
#define DIM 128
#define NPIX 409600
#define KCAND 100
#define RPAD 128
#define DSW 3200              // u32 words per downsampled row-mask (320*320 bits)
#define MOUT 40960000         // masks output elements (100*640*640)
#define NBLK 3200             // gemm blocks (one per 128-px tile)
#define FT_LD 104             // feat_t leading dim (non-pow2, 16B-aligned float4 rows)

// ---- workspace byte offsets ----
#define WS_TOPV    0          // f32[128] top_s
#define WS_TOPI    512        // i32[128] indices
#define WS_VALID   1024       // f32[128]
#define WS_KEEPF   1536       // f32[128]
#define WS_MNT     2048       // f32[128*128] mn, layout [d][r]
#define WS_META    67584      // f32[128*128] meta, layout [r][d]
#define WS_CNT     133120     // f64[128] seg pixel counts
#define WS_SSUM    134144     // f64[128] seg score sums
#define WS_INTER   135168     // f32[100*100] downsampled mask intersections
#define WS_APREP1  175168     // 64KB: pre-split/pre-swizzled bf16 hi/lo A (pre-NMS order)
#define WS_SCALE2  240704     // f32[128] final row scales (keep2)
#define WS_DS      241216     // u32[128*3200] bitpacked downsampled masks
#define WS_PART    1879616    // f32[3200*256] per-block stat partials (cnt|ssum)
#define WS_APREP2  1879616    // 64KB: post-NMS A prep; aliases part (dead after stats_reduce)
// total: 5,156,416 bytes (unchanged)

typedef short  s16x8  __attribute__((ext_vector_type(8)));
typedef float  f32x16 __attribute__((ext_vector_type(16)));

// even-bit compress: bit 2j -> bit j (inverse of morton spread)
__device__ __forceinline__ unsigned int compact16(unsigned int x) {
  x &= 0x55555555u;
  x = (x | (x >> 1)) & 0x33333333u;
  x = (x | (x >> 2)) & 0x0F0F0F0Fu;
  x = (x | (x >> 4)) & 0x00FF00FFu;
  x = (x | (x >> 8)) & 0x0000FFFFu;
  return x;
}

// Split A (fp32, [k][RPAD] layout) into bf16 hi/lo, writing the PRE-SWIZZLED
// global image of the gemm's LDS tile so staging is a linear 16B copy
// (global_load-friendly) and fragment ds_read_b128 is bank-minimal.
// dst layout: [c(2)][hl(2)][r(128)][u(8)] 16B units; unit (c,r,u) holds
// A[r][ c*64 + (u^(r&7))*8 + e ], e=0..7.
__device__ __forceinline__ void prep_a(const float* __restrict__ srcKR,
                                       const int* order,
                                       char* __restrict__ dst, int tid) {
  for (int t = tid; t < 2048; t += 256) {
    int r = t >> 4;
    int c = (t >> 3) & 1;
    int u = t & 7;
    int rs = r;
    bool zero = false;
    if (order) { if (r < KCAND) rs = order[r]; else zero = true; }
    union { s16x8 v; short s[8]; } H, L;
    #pragma unroll
    for (int e = 0; e < 8; ++e) {
      int k = c * 64 + ((u ^ (r & 7)) << 3) + e;
      float x = zero ? 0.0f : srcKR[k * RPAD + rs];
      unsigned int ux = __float_as_uint(x);
      unsigned int hb = ux & 0xFFFF0000u;          // truncate-to-bf16 (hi)
      float lo = x - __uint_as_float(hb);          // exact residual
      H.s[e] = (short)(hb >> 16);
      L.s[e] = (short)(__float_as_uint(lo) >> 16); // truncate-to-bf16 (lo)
    }
    *(s16x8*)(dst + c * 32768 + r * 128 + u * 16) = H.v;
    *(s16x8*)(dst + c * 32768 + 16384 + r * 128 + u * 16) = L.v;
  }
}

// ============ kernel 1: sigmoid + top-100 (radix histogram select) ============
__global__ __launch_bounds__(256) void topk_kernel(const float* __restrict__ pred, char* ws) {
  float* topv   = (float*)(ws + WS_TOPV);
  int*   topi   = (int*)(ws + WS_TOPI);
  float* validf = (float*)(ws + WS_VALID);

  __shared__ unsigned int hist[1024];
  __shared__ float cv[1024];
  __shared__ int ci[1024];
  __shared__ int scl[4];
  __shared__ unsigned int ncand;

  int tid = threadIdx.x;
  for (int b = tid; b < 1024; b += 256) hist[b] = 0;
  if (tid == 0) ncand = 0;
  __syncthreads();

  for (int k = tid; k < HW25600; k += 256) {
    float s = 1.0f / (1.0f + expf(-pred[k]));
    unsigned int u = __float_as_uint(s);
    atomicAdd(&hist[u >> 21], 1u);
  }
  __syncthreads();
  if (tid == 0) {
    int c = 0, B = 0;
    for (int b = 1023; b >= 0; --b) {
      int h = (int)hist[b];
      if (c + h >= KCAND) { B = b; break; }
      c += h;
    }
    scl[0] = B; scl[1] = c;
  }
  __syncthreads();
  int B = scl[0], cAb = scl[1];
  __syncthreads();
  for (int b = tid; b < 1024; b += 256) hist[b] = 0;
  __syncthreads();
  for (int k = tid; k < HW25600; k += 256) {
    float s = 1.0f / (1.0f + expf(-pred[k]));
    unsigned int u = __float_as_uint(s);
    if ((int)(u >> 21) == B) atomicAdd(&hist[(u >> 11) & 1023], 1u);
  }
  __syncthreads();
  if (tid == 0) {
    int target = KCAND - cAb;
    int c = 0, B2 = 0;
    for (int b = 1023; b >= 0; --b) {
      int h = (int)hist[b];
      if (c + h >= target) { B2 = b; break; }
      c += h;
    }
    scl[2] = B2;
  }
  __syncthreads();
  unsigned int thr = ((unsigned int)B << 21) | ((unsigned int)scl[2] << 11);
  for (int k = tid; k < HW25600; k += 256) {
    float s = 1.0f / (1.0f + expf(-pred[k]));
    unsigned int u = __float_as_uint(s);
    if (u >= thr) {
      unsigned int slot = atomicAdd(&ncand, 1u);
      if (slot < 1024u) { cv[slot] = s; ci[slot] = k; }
    }
  }
  __syncthreads();
  int nc = (int)(ncand < 1024u ? ncand : 1024u);
  for (int c = tid; c < nc; c += 256) {
    float v = cv[c]; int id = ci[c];
    int rk = 0;
    for (int o = 0; o < nc; ++o) {
      float u2 = cv[o]; int i2 = ci[o];
      rk += (int)((u2 > v) || (u2 == v && i2 < id));
    }
    if (rk < KCAND) {
      topv[rk] = v; topi[rk] = id;
      validf[rk] = (v > 0.75f) ? 1.0f : 0.0f;
    }
  }
  for (int r = tid; r < RPAD; r += 256)
    if (r >= KCAND) { topv[r] = 0.0f; topi[r] = 0; validf[r] = 0.0f; }
}

// ============ kernel 2: feat gather, cosine sim, dedup, meta kernels, mn + A-prep ============
// feat staged TRANSPOSED [d][i] with FT_LD=104 so norm loops (consecutive-i lanes)
// and sim j-reads (float4 over j) are LDS bank-conflict free (was 32-way at [i][128]).
__global__ __launch_bounds__(256) void fuse_kernel(const float* __restrict__ emb, char* ws) {
  int*   topi   = (int*)(ws + WS_TOPI);
  float* validfg= (float*)(ws + WS_VALID);
  float* keepfg = (float*)(ws + WS_KEEPF);
  float* mnt    = (float*)(ws + WS_MNT);
  float* metag  = (float*)(ws + WS_META);

  __shared__ __align__(16) float feat_t[DIM * FT_LD];   // 53,248 B, [d][i]
  __shared__ unsigned int lab[KCAND * 4];
  __shared__ unsigned int lkb[KCAND * 4];
  __shared__ float rinv[KCAND];
  __shared__ float valids[KCAND];
  __shared__ float keeps[KCAND];
  __shared__ float divis[KCAND];
  __shared__ float mnrm[KCAND];

  int tid = threadIdx.x;
  for (int t = tid; t < KCAND * 4; t += 256) { lab[t] = 0u; lkb[t] = 0u; }
  for (int i = tid; i < KCAND; i += 256) valids[i] = validfg[i];
  // gather: lanes consecutive i -> conflict-free LDS writes; scattered emb reads
  for (int t = tid; t < DIM * FT_LD; t += 256) {
    int d = t / FT_LD, i = t - d * FT_LD;
    feat_t[t] = (i < KCAND) ? emb[d * HW25600 + topi[i]] : 0.0f;
  }
  __syncthreads();
  // row norms: lanes consecutive i, stride-4B reads -> conflict-free
  for (int i = tid; i < KCAND; i += 256) {
    float n2 = 0.0f;
    for (int d = 0; d < DIM; ++d) { float f = feat_t[d * FT_LD + i]; n2 = fmaf(f, f, n2); }
    rinv[i] = 1.0f / fmaxf(sqrtf(n2), 1e-8f);
  }
  __syncthreads();
  // sim: thread = (i, j4 block of 4 js); ds_read_b128 over j, broadcast over i
  for (int t = tid; t < KCAND * 25; t += 256) {
    int i = t / 25, j4 = t - i * 25;
    int j0 = j4 * 4;
    if (valids[i] > 0.0f && j0 + 3 >= i) {
      float4 dp = make_float4(0.f, 0.f, 0.f, 0.f);
      for (int d = 0; d < DIM; ++d) {
        float fi = feat_t[d * FT_LD + i];
        float4 fj = *(const float4*)&feat_t[d * FT_LD + j0];
        dp.x = fmaf(fi, fj.x, dp.x); dp.y = fmaf(fi, fj.y, dp.y);
        dp.z = fmaf(fi, fj.z, dp.z); dp.w = fmaf(fi, fj.w, dp.w);
      }
      float ri = rinv[i];
      float s0 = dp.x * ri * rinv[j0];
      float s1 = dp.y * ri * rinv[j0 + 1];
      float s2 = dp.z * ri * rinv[j0 + 2];
      float s3 = dp.w * ri * rinv[j0 + 3];
      #pragma unroll
      for (int c = 0; c < 4; ++c) {
        int j = j0 + c;
        float sv = (c == 0) ? s0 : (c == 1) ? s1 : (c == 2) ? s2 : s3;
        if (j >= i && valids[j] > 0.0f && sv >= 0.75f)
          atomicOr(&lab[i * 4 + (j >> 5)], 1u << (j & 31));
      }
    }
  }
  __syncthreads();
  // column cumsum < 2 (dedup), keep = diag(cum) & valid
  for (int j = tid; j < KCAND; j += 256) {
    int c = 0;
    for (int i = 0; i < KCAND; ++i) {
      unsigned int l = (lab[i*4 + (j>>5)] >> (j & 31)) & 1u;
      c += (int)l;
      if (l && c < 2) atomicOr(&lkb[i*4 + (j>>5)], 1u << (j & 31));
      if (i == j) keeps[j] = (c < 2 && valids[j] > 0.0f) ? 1.0f : 0.0f;
    }
  }
  __syncthreads();
  for (int i = tid; i < KCAND; i += 256) {
    int cnt = 0;
    for (int w = 0; w < 4; ++w) cnt += __popc(lkb[i*4+w]);
    divis[i] = fmaxf((keeps[i] > 0.0f) ? (float)cnt : 0.0f, 1.0f);
  }
  __syncthreads();
  // meta = (label_k @ feat) / norm  (iterate set bits; ~1 bit/row typical)
  for (int t = tid; t < KCAND*DIM; t += 256) {
    int i = t >> 7, d = t & 127;
    float s = 0.0f;
    if (keeps[i] > 0.0f) {
      for (int w = 0; w < 4; ++w) {
        unsigned int m = lkb[i*4+w];
        while (m) {
          int j = (w << 5) + __ffs(m) - 1;
          m &= m - 1u;
          s += feat_t[d * FT_LD + j];
        }
      }
    }
    metag[t] = s / divis[i];
  }
  __syncthreads();
  for (int i = tid; i < KCAND; i += 256) {
    float n2 = 0.0f;
    for (int d = 0; d < DIM; ++d) { float f = metag[i*DIM+d]; n2 = fmaf(f, f, n2); }
    mnrm[i] = fmaxf(sqrtf(n2), 1e-8f);
  }
  __syncthreads();
  // mn transposed [d][r], rows 100..127 zero-padded
  for (int t = tid; t < RPAD*DIM; t += 256) {
    int d = t >> 7, r = t & 127;
    float v = 0.0f;
    if (r < KCAND) v = metag[r*DIM + d] / mnrm[r];
    mnt[d*RPAD + r] = v;
  }
  for (int r = tid; r < RPAD; r += 256) keepfg[r] = (r < KCAND) ? keeps[r] : 0.0f;
  __syncthreads();
  // split/swizzle A for the MFMA gemm (pre-NMS row order)
  prep_a(mnt, (const int*)0, ws + WS_APREP1, tid);
}

// ============ kernel 3/7: MFMA GEMM sigmoid(mn @ enc) via split-bf16 ============
// Block = 128-px tile, 4 waves; wave w owns px [bx*128 + w*32, +32).
// Per wave: 4 row-tiles (m) x 8 k-steps x 3 products of mfma_f32_32x32x16_bf16.
// A (mn hi/lo) staged per 64-k chunk from pre-swizzled global (32KB LDS, linear copy).
// B (enc) loaded straight into fragments (8 x dword, 2x128B segments/instr) and
// hi/lo-split in registers with bit-ops only.
template<bool STATS>
__global__ __launch_bounds__(256, 3) void gemm_kernel(const float* __restrict__ enc,
                                                      char* __restrict__ ws,
                                                      float* __restrict__ out) {
  __shared__ __align__(16) short alds[16384];   // 32KB: [hl][r(128)][u(8)] 16B units
  __shared__ float scale_s[RPAD];
  __shared__ float red_s[2][RPAD][4];           // stats partials per wave
  __shared__ unsigned int dsw_s[RPAD][2];       // ds bitmask words per block

  const char*  aprep = ws + (STATS ? WS_APREP1 : WS_APREP2);
  const float* ssrc  = (const float*)(ws + (STATS ? WS_KEEPF : WS_SCALE2));

  int tid  = threadIdx.x;
  int lane = tid & 63;
  int w    = tid >> 6;       // wave 0..3
  int cl   = lane & 31;      // MFMA column (px) / A row within tile
  int hgrp = lane >> 5;      // k-subgroup of 8
  int bx   = blockIdx.x;
  int px   = bx * 128 + w * 32 + cl;

  if (tid < RPAD) scale_s[tid] = ssrc[tid];
  if (STATS) dsw_s[tid >> 1][tid & 1] = 0u;

  f32x16 acc[4];
  #pragma unroll
  for (int mt = 0; mt < 4; ++mt) acc[mt] = (f32x16)0.0f;

  const float4* asrc = (const float4*)aprep;
  for (int c = 0; c < 2; ++c) {
    __syncthreads();                       // protect alds reuse
    #pragma unroll
    for (int i = 0; i < 8; ++i)
      ((float4*)alds)[tid + 256 * i] = asrc[c * 2048 + tid + 256 * i];
    __syncthreads();

    const float* ep = enc + (size_t)(c * 64 + hgrp * 8) * NPIX + px;
    #pragma unroll
    for (int ks = 0; ks < 4; ++ks) {
      // B fragment: k = c*64 + ks*16 + hgrp*8 + i
      float bv[8];
      #pragma unroll
      for (int i = 0; i < 8; ++i) bv[i] = ep[(size_t)(ks * 16 + i) * NPIX];
      union { s16x8 v; unsigned int u[4]; } Bh, Bl;
      #pragma unroll
      for (int i = 0; i < 4; ++i) {
        unsigned int u0 = __float_as_uint(bv[2*i]);
        unsigned int u1 = __float_as_uint(bv[2*i+1]);
        unsigned int h0 = u0 & 0xFFFF0000u, h1 = u1 & 0xFFFF0000u;
        float l0 = bv[2*i]   - __uint_as_float(h0);
        float l1 = bv[2*i+1] - __uint_as_float(h1);
        Bh.u[i] = (h0 >> 16) | h1;
        Bl.u[i] = (__float_as_uint(l0) >> 16) | (__float_as_uint(l1) & 0xFFFF0000u);
      }
      // A fragments (hi+lo) for 4 row-tiles; swizzled unit index
      s16x8 ah[4], al[4];
      #pragma unroll
      for (int mt = 0; mt < 4; ++mt) {
        int r = mt * 32 + cl;
        int u = (ks * 2 + hgrp) ^ (r & 7);
        const short* ap = alds + r * 64 + u * 8;
        ah[mt] = *(const s16x8*)ap;
        al[mt] = *(const s16x8*)(ap + 8192);
      }
      // 3-product split accumulation; consecutive MFMAs hit different acc regs
      #pragma unroll
      for (int mt = 0; mt < 4; ++mt)
        acc[mt] = __builtin_amdgcn_mfma_f32_32x32x16_bf16(ah[mt], Bh.v, acc[mt], 0, 0, 0);
      #pragma unroll
      for (int mt = 0; mt < 4; ++mt)
        acc[mt] = __builtin_amdgcn_mfma_f32_32x32x16_bf16(ah[mt], Bl.v, acc[mt], 0, 0, 0);
      #pragma unroll
      for (int mt = 0; mt < 4; ++mt)
        acc[mt] = __builtin_amdgcn_mfma_f32_32x32x16_bf16(al[mt], Bh.v, acc[mt], 0, 0, 0);
    }
  }

  // D layout (verified): col = lane&31 (= our px), row = (q&3) + 8*(q>>2) + 4*hgrp
  int y = bx / 5, xw = bx - y * 5;
  bool yeven = (y & 1) == 0;
  if (STATS) {
    #pragma unroll
    for (int mt = 0; mt < 4; ++mt) {
      #pragma unroll
      for (int q = 0; q < 16; ++q) {
        int r = mt * 32 + (q & 3) + 8 * (q >> 2) + 4 * hgrp;
        float s = scale_s[r] * (1.0f / (1.0f + expf(-acc[mt][q])));
        bool bb = s > 0.45f;
        unsigned long long bm = __ballot(bb);
        unsigned int hbits = (unsigned int)(bm >> (hgrp * 32));
        float ssum = bb ? s : 0.0f;
        #pragma unroll
        for (int off = 1; off <= 16; off <<= 1) ssum += __shfl_xor(ssum, off);
        if ((lane & 31) == 0) {
          red_s[0][r][w] = (float)__popc(hbits);
          red_s[1][r][w] = ssum;
        }
        if (yeven) {
          unsigned int ex = compact16(hbits);   // even-x bits of this wave's 32 px
          if ((lane & 31) == 0)
            atomicOr(&dsw_s[r][w >> 1], ex << ((w & 1) * 16));
        }
      }
    }
    __syncthreads();
    float* part = (float*)(ws + WS_PART);
    unsigned int* ds32 = (unsigned int*)(ws + WS_DS);
    int r = tid & 127, st = tid >> 7;
    part[bx * 256 + st * 128 + r] =
        red_s[st][r][0] + red_s[st][r][1] + red_s[st][r][2] + red_s[st][r][3];
    if (yeven) {
      int rr = tid >> 1, wd = tid & 1;
      ds32[rr * DSW + (y >> 1) * 10 + xw * 2 + wd] = dsw_s[rr][wd];
    }
  } else {
    #pragma unroll
    for (int mt = 0; mt < 4; ++mt) {
      #pragma unroll
      for (int q = 0; q < 16; ++q) {
        int r = mt * 32 + (q & 3) + 8 * (q >> 2) + 4 * hgrp;
        if (r < KCAND) {
          float o = scale_s[r] * (1.0f / (1.0f + expf(-acc[mt][q])));
          out[(size_t)r * NPIX + px] = o;
        }
      }
    }
  }
}

// ============ kernel 4: deterministic f64 reduce of per-block stat partials ============
__global__ __launch_bounds__(256) void stats_reduce_kernel(char* ws) {
  const float* part = (const float*)(ws + WS_PART);
  double* cntd  = (double*)(ws + WS_CNT);
  double* ssumd = (double*)(ws + WS_SSUM);
  __shared__ double cs_[256], ss_[256];
  int tid = threadIdx.x;
  int r = blockIdx.x;
  double c = 0.0, s = 0.0;
  for (int b = tid; b < NBLK; b += 256) {
    c += (double)part[b * 256 + r];
    s += (double)part[b * 256 + RPAD + r];
  }
  cs_[tid] = c; ss_[tid] = s;
  __syncthreads();
  for (int o = 128; o >= 1; o >>= 1) {
    if (tid < o) { cs_[tid] += cs_[tid + o]; ss_[tid] += ss_[tid + o]; }
    __syncthreads();
  }
  if (tid == 0) { cntd[r] = cs_[0]; ssumd[r] = ss_[0]; }
}

// ============ kernel 5: pairwise mask intersections (popcount over bitpacked ds) ============
__global__ __launch_bounds__(256) void inter_kernel(char* ws) {
  int i = blockIdx.y, j = blockIdx.x;
  if (j < i) return;
  const unsigned int* ds32 = (const unsigned int*)(ws + WS_DS);
  float* inter = (float*)(ws + WS_INTER);
  const unsigned int* a = ds32 + i * DSW;
  const unsigned int* b = ds32 + j * DSW;
  int s = 0;
  for (int w = threadIdx.x; w < DSW; w += 256) s += __popc(a[w] & b[w]);
  #pragma unroll
  for (int off = 32; off >= 1; off >>= 1) s += __shfl_xor(s, off);
  __shared__ int red[4];
  int lane = threadIdx.x & 63, wv = threadIdx.x >> 6;
  if (lane == 0) red[wv] = s;
  __syncthreads();
  if (threadIdx.x == 0) inter[i*KCAND + j] = (float)(red[0] + red[1] + red[2] + red[3]);
}

// ============ kernel 6: score/sort/matrix-NMS, small outputs, build A2/scale2 ============
__global__ __launch_bounds__(256) void nms_kernel(char* ws, float* __restrict__ out) {
  float* topv   = (float*)(ws + WS_TOPV);
  float* keepfg = (float*)(ws + WS_KEEPF);
  double* cntd  = (double*)(ws + WS_CNT);
  double* ssumd = (double*)(ws + WS_SSUM);
  float* inter  = (float*)(ws + WS_INTER);
  float* mnt    = (float*)(ws + WS_MNT);
  float* scale2 = (float*)(ws + WS_SCALE2);

  __shared__ float iou_s[KCAND*KCAND];   // 40 KB
  __shared__ float sc0[KCAND], sc_s[KCAND], keep_s[KCAND], s2_s[KCAND];
  __shared__ float comp_[KCAND], k2f_[KCAND];
  __shared__ int order_[KCAND];

  int tid = threadIdx.x;
  for (int r = tid; r < KCAND; r += 256) {
    double c = cntd[r], s = ssumd[r];
    float seg = (float)(s / fmax(c, 1.0));
    sc0[r] = topv[r] * seg;
  }
  __syncthreads();
  for (int i = tid; i < KCAND; i += 256) {
    float v = sc0[i]; int rk = 0;
    for (int j = 0; j < KCAND; ++j) {
      float u = sc0[j];
      rk += (int)((u > v) || (u == v && j < i));
    }
    order_[rk] = i;
  }
  __syncthreads();
  for (int i = tid; i < KCAND; i += 256) {
    int oi = order_[i];
    sc_s[i]   = sc0[oi];
    keep_s[i] = keepfg[oi];
    s2_s[i]   = inter[oi*KCAND + oi];
  }
  __syncthreads();
  for (int t = tid; t < KCAND*KCAND; t += 256) {
    int i = t / KCAND, j = t - i*KCAND;
    float v = 0.0f;
    if (i < j) {
      int oi = order_[i], oj = order_[j];
      int a = min(oi, oj), b = max(oi, oj);
      float iv = inter[a*KCAND + b];
      float un = s2_s[i] + s2_s[j] - iv;
      v = iv / fmaxf(un, 1e-6f);
    }
    iou_s[t] = v;
  }
  __syncthreads();
  for (int i = tid; i < KCAND; i += 256) {
    float m = 0.0f;
    for (int r = 0; r < KCAND; ++r) m = fmaxf(m, iou_s[r*KCAND + i]);
    comp_[i] = m;
  }
  __syncthreads();
  for (int j = tid; j < KCAND; j += 256) {
    float mv = 3.4e38f;
    for (int i = 0; i < KCAND; ++i) {
      float io = iou_s[i*KCAND + j];
      float cm = comp_[i];
      float ratio = expf(-2.0f*io*io) / expf(-2.0f*cm*cm);
      mv = fminf(mv, ratio);
    }
    float sc2 = sc_s[j] * mv;
    bool k2 = (sc2 >= 0.05f) && (keep_s[j] > 0.5f);
    float kf = k2 ? 1.0f : 0.0f;
    k2f_[j] = kf;
    out[MOUT + j] = sc2 * kf;                 // scores
    out[MOUT + KCAND + j] = 0.0f;             // labels
    out[MOUT + 2*KCAND + j] = kf;             // keep
  }
  __syncthreads();
  // split/swizzle permuted A for the final MFMA gemm (replaces mn2t)
  prep_a(mnt, order_, ws + WS_APREP2, tid);
  for (int r = tid; r < RPAD; r += 256) scale2[r] = (r < KCAND) ? k2f_[r] : 0.0f;
}

extern "C" void kernel_launch(void* const* d_in, const int* in_sizes, int n_in,
                              void* d_out, int out_size, void* d_ws, size_t ws_size,
                              hipStream_t stream) {
  const float* pred = (const float*)d_in[0];
  const float* emb  = (const float*)d_in[1];
  const float* enc  = (const float*)d_in[2];
  float* out = (float*)d_out;
  char* ws = (char*)d_ws;

  topk_kernel<<<dim3(1), dim3(256), 0, stream>>>(pred, ws);
  fuse_kernel<<<dim3(1), dim3(256), 0, stream>>>(emb, ws);
  gemm_kernel<true><<<dim3(NBLK), dim3(256), 0, stream>>>(enc, ws, out);
  stats_reduce_kernel<<<dim3(RPAD), dim3(256), 0, stream>>>(ws);
  inter_kernel<<<dim3(100, 100), dim3(256), 0, stream>>>(ws);
  nms_kernel<<<dim3(1), dim3(256), 0, stream>>>(ws, out);
  gemm_kernel<false><<<dim3(NBLK), dim3(256), 0, stream>>>(enc, ws, out);
}

// Round 5
// 768.831 us; speedup vs baseline: 1.3906x; 1.0488x over previous
//
#include <hip/hip_runtime.h>
#include <math.h>

#define HW25600 25600
#define DIM 128
#define NPIX 409600
#define KCAND 100
#define RPAD 128
#define DSW 3200              // u32 words per downsampled row-mask (320*320 bits)
#define MOUT 40960000         // masks output elements (100*640*640)
#define NBLK 3200             // gemm blocks (one per 128-px tile)
#define FT_LD 104             // feat_t leading dim (non-pow2, 16B-aligned float4 rows)

// ---- workspace byte offsets ----
#define WS_TOPV    0          // f32[128] top_s
#define WS_TOPI    512        // i32[128] indices
#define WS_VALID   1024       // f32[128]
#define WS_KEEPF   1536      // f32[128]
#define WS_MNT     2048       // f32[128*128] mn, layout [d][r]
#define WS_META    67584      // f32[128*128] meta scratch (fuse)
#define WS_CNT     133120     // f64[128] seg pixel counts
#define WS_SSUM    134144     // f64[128] seg score sums
#define WS_INTER   135168     // f32[100*100] downsampled mask intersections
#define WS_APREP1  175168     // 64KB: pre-split/pre-swizzled bf16 hi/lo A (pre-NMS order)
#define WS_SCALE2  240704     // f32[128] final row scales (keep2)
#define WS_DS      241216     // u32[128*3200] bitpacked downsampled masks
#define WS_PART    1879616    // f32[3200*256] per-block stat partials (cnt|ssum)
#define WS_APREP2  1879616    // 64KB: post-NMS A prep; aliases part (dead after stats_reduce)
// total: 5,156,416 bytes (unchanged)

typedef short  s16x8  __attribute__((ext_vector_type(8)));
typedef float  f32x16 __attribute__((ext_vector_type(16)));

// even-bit compress: bit 2j -> bit j (inverse of morton spread)
__device__ __forceinline__ unsigned int compact16(unsigned int x) {
  x &= 0x55555555u;
  x = (x | (x >> 1)) & 0x33333333u;
  x = (x | (x >> 2)) & 0x0F0F0F0Fu;
  x = (x | (x >> 4)) & 0x00FF00FFu;
  x = (x | (x >> 8)) & 0x0000FFFFu;
  return x;
}

// Split A (fp32, [k][RPAD] layout) into bf16 hi/lo, writing the PRE-SWIZZLED
// global image of the gemm's LDS tile. dst layout: [c(2)][hl(2)][r(128)][u(8)]
// 16B units; unit (c,r,u) holds A[r][ c*64 + (u^(r&7))*8 + e ], e=0..7.
__device__ __forceinline__ void prep_a(const float* __restrict__ srcKR,
                                       const int* order,
                                       char* __restrict__ dst, int tid) {
  for (int t = tid; t < 2048; t += 256) {
    int r = t >> 4;
    int c = (t >> 3) & 1;
    int u = t & 7;
    int rs = r;
    bool zero = false;
    if (order) { if (r < KCAND) rs = order[r]; else zero = true; }
    union { s16x8 v; short s[8]; } H, L;
    #pragma unroll
    for (int e = 0; e < 8; ++e) {
      int k = c * 64 + ((u ^ (r & 7)) << 3) + e;
      float x = zero ? 0.0f : srcKR[k * RPAD + rs];
      unsigned int ux = __float_as_uint(x);
      unsigned int hb = ux & 0xFFFF0000u;          // truncate-to-bf16 (hi)
      float lo = x - __uint_as_float(hb);          // exact residual
      H.s[e] = (short)(hb >> 16);
      L.s[e] = (short)(__float_as_uint(lo) >> 16); // truncate-to-bf16 (lo)
    }
    *(s16x8*)(dst + c * 32768 + r * 128 + u * 16) = H.v;
    *(s16x8*)(dst + c * 32768 + 16384 + r * 128 + u * 16) = L.v;
  }
}

// ============ kernel 1: sigmoid + top-100 (radix histogram select) ============
// Same proven 256-thread control flow as the passing baseline; passes now use
// float4 loads with compile-time trip count (25) so 25 loads are in flight
// (was: scalar loads, 1 outstanding -> ~150us of pure latency serialization).
__global__ __launch_bounds__(256) void topk_kernel(const float* __restrict__ pred, char* ws) {
  float* topv   = (float*)(ws + WS_TOPV);
  int*   topi   = (int*)(ws + WS_TOPI);
  float* validf = (float*)(ws + WS_VALID);

  __shared__ unsigned int hist[1024];
  __shared__ float cv[1024];
  __shared__ int ci[1024];
  __shared__ int scl[4];
  __shared__ unsigned int ncand;

  int tid = threadIdx.x;
  for (int b = tid; b < 1024; b += 256) hist[b] = 0;
  if (tid == 0) ncand = 0;
  __syncthreads();

  const float4* pred4 = (const float4*)pred;

  // pass A: histogram on bits[30:21] (sigmoid in (0,1) -> positive, monotone bits)
  #pragma unroll
  for (int t = tid; t < HW25600 / 4; t += 256) {
    float4 p = pred4[t];
    unsigned int u0 = __float_as_uint(1.0f / (1.0f + expf(-p.x)));
    unsigned int u1 = __float_as_uint(1.0f / (1.0f + expf(-p.y)));
    unsigned int u2 = __float_as_uint(1.0f / (1.0f + expf(-p.z)));
    unsigned int u3 = __float_as_uint(1.0f / (1.0f + expf(-p.w)));
    atomicAdd(&hist[u0 >> 21], 1u);
    atomicAdd(&hist[u1 >> 21], 1u);
    atomicAdd(&hist[u2 >> 21], 1u);
    atomicAdd(&hist[u3 >> 21], 1u);
  }
  __syncthreads();
  if (tid == 0) {
    int c = 0, B = 0;
    for (int b = 1023; b >= 0; --b) {
      int h = (int)hist[b];
      if (c + h >= KCAND) { B = b; break; }
      c += h;
    }
    scl[0] = B; scl[1] = c;
  }
  __syncthreads();
  int B = scl[0], cAb = scl[1];
  __syncthreads();
  for (int b = tid; b < 1024; b += 256) hist[b] = 0;
  __syncthreads();
  // pass B: refine within bin B on bits[20:11]
  #pragma unroll
  for (int t = tid; t < HW25600 / 4; t += 256) {
    float4 p = pred4[t];
    unsigned int u0 = __float_as_uint(1.0f / (1.0f + expf(-p.x)));
    unsigned int u1 = __float_as_uint(1.0f / (1.0f + expf(-p.y)));
    unsigned int u2 = __float_as_uint(1.0f / (1.0f + expf(-p.z)));
    unsigned int u3 = __float_as_uint(1.0f / (1.0f + expf(-p.w)));
    if ((int)(u0 >> 21) == B) atomicAdd(&hist[(u0 >> 11) & 1023], 1u);
    if ((int)(u1 >> 21) == B) atomicAdd(&hist[(u1 >> 11) & 1023], 1u);
    if ((int)(u2 >> 21) == B) atomicAdd(&hist[(u2 >> 11) & 1023], 1u);
    if ((int)(u3 >> 21) == B) atomicAdd(&hist[(u3 >> 11) & 1023], 1u);
  }
  __syncthreads();
  if (tid == 0) {
    int target = KCAND - cAb;
    int c = 0, B2 = 0;
    for (int b = 1023; b >= 0; --b) {
      int h = (int)hist[b];
      if (c + h >= target) { B2 = b; break; }
      c += h;
    }
    scl[2] = B2;
  }
  __syncthreads();
  unsigned int thr = ((unsigned int)B << 21) | ((unsigned int)scl[2] << 11);
  // pass C: collect candidates (superset of top-100)
  #pragma unroll
  for (int t = tid; t < HW25600 / 4; t += 256) {
    float4 p = pred4[t];
    float s0 = 1.0f / (1.0f + expf(-p.x));
    float s1 = 1.0f / (1.0f + expf(-p.y));
    float s2 = 1.0f / (1.0f + expf(-p.z));
    float s3 = 1.0f / (1.0f + expf(-p.w));
    if (__float_as_uint(s0) >= thr) {
      unsigned int sl = atomicAdd(&ncand, 1u);
      if (sl < 1024u) { cv[sl] = s0; ci[sl] = t * 4; }
    }
    if (__float_as_uint(s1) >= thr) {
      unsigned int sl = atomicAdd(&ncand, 1u);
      if (sl < 1024u) { cv[sl] = s1; ci[sl] = t * 4 + 1; }
    }
    if (__float_as_uint(s2) >= thr) {
      unsigned int sl = atomicAdd(&ncand, 1u);
      if (sl < 1024u) { cv[sl] = s2; ci[sl] = t * 4 + 2; }
    }
    if (__float_as_uint(s3) >= thr) {
      unsigned int sl = atomicAdd(&ncand, 1u);
      if (sl < 1024u) { cv[sl] = s3; ci[sl] = t * 4 + 3; }
    }
  }
  __syncthreads();
  int nc = (int)(ncand < 1024u ? ncand : 1024u);
  // pass D: exact rank (descending value, ascending index) == lax.top_k order
  for (int c = tid; c < nc; c += 256) {
    float v = cv[c]; int id = ci[c];
    int rk = 0;
    for (int o = 0; o < nc; ++o) {
      float u2 = cv[o]; int i2 = ci[o];
      rk += (int)((u2 > v) || (u2 == v && i2 < id));
    }
    if (rk < KCAND) {
      topv[rk] = v; topi[rk] = id;
      validf[rk] = (v > 0.75f) ? 1.0f : 0.0f;
    }
  }
  for (int r = tid; r < RPAD; r += 256)
    if (r >= KCAND) { topv[r] = 0.0f; topi[r] = 0; validf[r] = 0.0f; }
}

// ============ kernel 2: feat gather, cosine sim, dedup, meta kernels, mn + A-prep ============
// feat staged TRANSPOSED [d][i] with FT_LD=104 so norm loops (consecutive-i lanes)
// and sim j-reads (float4 over j) are LDS bank-conflict free.
__global__ __launch_bounds__(256) void fuse_kernel(const float* __restrict__ emb, char* ws) {
  int*   topi   = (int*)(ws + WS_TOPI);
  float* validfg= (float*)(ws + WS_VALID);
  float* keepfg = (float*)(ws + WS_KEEPF);
  float* mnt    = (float*)(ws + WS_MNT);
  float* metag  = (float*)(ws + WS_META);

  __shared__ __align__(16) float feat_t[DIM * FT_LD];   // 53,248 B, [d][i]
  __shared__ unsigned int lab[KCAND * 4];
  __shared__ unsigned int lkb[KCAND * 4];
  __shared__ float rinv[KCAND];
  __shared__ float valids[KCAND];
  __shared__ float keeps[KCAND];
  __shared__ float divis[KCAND];
  __shared__ float mnrm[KCAND];

  int tid = threadIdx.x;
  for (int t = tid; t < KCAND * 4; t += 256) { lab[t] = 0u; lkb[t] = 0u; }
  for (int i = tid; i < KCAND; i += 256) valids[i] = validfg[i];
  for (int t = tid; t < DIM * FT_LD; t += 256) {
    int d = t / FT_LD, i = t - d * FT_LD;
    feat_t[t] = (i < KCAND) ? emb[d * HW25600 + topi[i]] : 0.0f;
  }
  __syncthreads();
  for (int i = tid; i < KCAND; i += 256) {
    float n2 = 0.0f;
    for (int d = 0; d < DIM; ++d) { float f = feat_t[d * FT_LD + i]; n2 = fmaf(f, f, n2); }
    rinv[i] = 1.0f / fmaxf(sqrtf(n2), 1e-8f);
  }
  __syncthreads();
  // sim: thread = (i, j4 block of 4 js); ds_read_b128 over j, broadcast over i
  for (int t = tid; t < KCAND * 25; t += 256) {
    int i = t / 25, j4 = t - i * 25;
    int j0 = j4 * 4;
    if (valids[i] > 0.0f && j0 + 3 >= i) {
      float4 dp = make_float4(0.f, 0.f, 0.f, 0.f);
      for (int d = 0; d < DIM; ++d) {
        float fi = feat_t[d * FT_LD + i];
        float4 fj = *(const float4*)&feat_t[d * FT_LD + j0];
        dp.x = fmaf(fi, fj.x, dp.x); dp.y = fmaf(fi, fj.y, dp.y);
        dp.z = fmaf(fi, fj.z, dp.z); dp.w = fmaf(fi, fj.w, dp.w);
      }
      float ri = rinv[i];
      float s0 = dp.x * ri * rinv[j0];
      float s1 = dp.y * ri * rinv[j0 + 1];
      float s2 = dp.z * ri * rinv[j0 + 2];
      float s3 = dp.w * ri * rinv[j0 + 3];
      #pragma unroll
      for (int c = 0; c < 4; ++c) {
        int j = j0 + c;
        float svv = (c == 0) ? s0 : (c == 1) ? s1 : (c == 2) ? s2 : s3;
        if (j >= i && valids[j] > 0.0f && svv >= 0.75f)
          atomicOr(&lab[i * 4 + (j >> 5)], 1u << (j & 31));
      }
    }
  }
  __syncthreads();
  // column cumsum < 2 (dedup), keep = diag(cum) & valid
  for (int j = tid; j < KCAND; j += 256) {
    int c = 0;
    for (int i = 0; i < KCAND; ++i) {
      unsigned int l = (lab[i*4 + (j>>5)] >> (j & 31)) & 1u;
      c += (int)l;
      if (l && c < 2) atomicOr(&lkb[i*4 + (j>>5)], 1u << (j & 31));
      if (i == j) keeps[j] = (c < 2 && valids[j] > 0.0f) ? 1.0f : 0.0f;
    }
  }
  __syncthreads();
  for (int i = tid; i < KCAND; i += 256) {
    int cnt = 0;
    for (int w = 0; w < 4; ++w) cnt += __popc(lkb[i*4+w]);
    divis[i] = fmaxf((keeps[i] > 0.0f) ? (float)cnt : 0.0f, 1.0f);
  }
  __syncthreads();
  for (int t = tid; t < KCAND*DIM; t += 256) {
    int i = t >> 7, d = t & 127;
    float s = 0.0f;
    if (keeps[i] > 0.0f) {
      for (int w = 0; w < 4; ++w) {
        unsigned int m = lkb[i*4+w];
        while (m) {
          int j = (w << 5) + __ffs(m) - 1;
          m &= m - 1u;
          s += feat_t[d * FT_LD + j];
        }
      }
    }
    metag[t] = s / divis[i];
  }
  __syncthreads();
  for (int i = tid; i < KCAND; i += 256) {
    float n2 = 0.0f;
    for (int d = 0; d < DIM; ++d) { float f = metag[i*DIM+d]; n2 = fmaf(f, f, n2); }
    mnrm[i] = fmaxf(sqrtf(n2), 1e-8f);
  }
  __syncthreads();
  for (int t = tid; t < RPAD*DIM; t += 256) {
    int d = t >> 7, r = t & 127;
    float v = 0.0f;
    if (r < KCAND) v = metag[r*DIM + d] / mnrm[r];
    mnt[d*RPAD + r] = v;
  }
  for (int r = tid; r < RPAD; r += 256) keepfg[r] = (r < KCAND) ? keeps[r] : 0.0f;
  __syncthreads();
  prep_a(mnt, (const int*)0, ws + WS_APREP1, tid);
}

// ============ kernel 3/7: MFMA GEMM sigmoid(mn @ enc) via split-bf16 ============
// Block = 128-px tile, 4 waves; wave w owns px [bx*128 + w*32, +32).
// Per wave: 4 row-tiles (m) x 8 k-steps x 3 products of mfma_f32_32x32x16_bf16.
template<bool STATS>
__global__ __launch_bounds__(256, 3) void gemm_kernel(const float* __restrict__ enc,
                                                      char* __restrict__ ws,
                                                      float* __restrict__ out) {
  __shared__ __align__(16) short alds[16384];   // 32KB: [hl][r(128)][u(8)] 16B units
  __shared__ float scale_s[RPAD];
  __shared__ float red_s[2][RPAD][4];           // stats partials per wave
  __shared__ unsigned int dsw_s[RPAD][2];       // ds bitmask words per block

  const char*  aprep = ws + (STATS ? WS_APREP1 : WS_APREP2);
  const float* ssrc  = (const float*)(ws + (STATS ? WS_KEEPF : WS_SCALE2));

  int tid  = threadIdx.x;
  int lane = tid & 63;
  int w    = tid >> 6;       // wave 0..3
  int cl   = lane & 31;      // MFMA column (px) / A row within tile
  int hgrp = lane >> 5;      // k-subgroup of 8
  int bx   = blockIdx.x;
  int px   = bx * 128 + w * 32 + cl;

  if (tid < RPAD) scale_s[tid] = ssrc[tid];
  if (STATS) dsw_s[tid >> 1][tid & 1] = 0u;

  f32x16 acc[4];
  #pragma unroll
  for (int mt = 0; mt < 4; ++mt) acc[mt] = (f32x16)0.0f;

  const float4* asrc = (const float4*)aprep;
  for (int c = 0; c < 2; ++c) {
    __syncthreads();                       // protect alds reuse
    #pragma unroll
    for (int i = 0; i < 8; ++i)
      ((float4*)alds)[tid + 256 * i] = asrc[c * 2048 + tid + 256 * i];
    __syncthreads();

    const float* ep = enc + (size_t)(c * 64 + hgrp * 8) * NPIX + px;
    #pragma unroll
    for (int ks = 0; ks < 4; ++ks) {
      // B fragment: k = c*64 + ks*16 + hgrp*8 + i
      float bv[8];
      #pragma unroll
      for (int i = 0; i < 8; ++i) bv[i] = ep[(size_t)(ks * 16 + i) * NPIX];
      union { s16x8 v; unsigned int u[4]; } Bh, Bl;
      #pragma unroll
      for (int i = 0; i < 4; ++i) {
        unsigned int u0 = __float_as_uint(bv[2*i]);
        unsigned int u1 = __float_as_uint(bv[2*i+1]);
        unsigned int h0 = u0 & 0xFFFF0000u, h1 = u1 & 0xFFFF0000u;
        float l0 = bv[2*i]   - __uint_as_float(h0);
        float l1 = bv[2*i+1] - __uint_as_float(h1);
        Bh.u[i] = (h0 >> 16) | h1;
        Bl.u[i] = (__float_as_uint(l0) >> 16) | (__float_as_uint(l1) & 0xFFFF0000u);
      }
      s16x8 ah[4], al[4];
      #pragma unroll
      for (int mt = 0; mt < 4; ++mt) {
        int r = mt * 32 + cl;
        int u = (ks * 2 + hgrp) ^ (r & 7);
        const short* ap = alds + r * 64 + u * 8;
        ah[mt] = *(const s16x8*)ap;
        al[mt] = *(const s16x8*)(ap + 8192);
      }
      #pragma unroll
      for (int mt = 0; mt < 4; ++mt)
        acc[mt] = __builtin_amdgcn_mfma_f32_32x32x16_bf16(ah[mt], Bh.v, acc[mt], 0, 0, 0);
      #pragma unroll
      for (int mt = 0; mt < 4; ++mt)
        acc[mt] = __builtin_amdgcn_mfma_f32_32x32x16_bf16(ah[mt], Bl.v, acc[mt], 0, 0, 0);
      #pragma unroll
      for (int mt = 0; mt < 4; ++mt)
        acc[mt] = __builtin_amdgcn_mfma_f32_32x32x16_bf16(al[mt], Bh.v, acc[mt], 0, 0, 0);
    }
  }

  // D layout (verified): col = lane&31 (= our px), row = (q&3) + 8*(q>>2) + 4*hgrp
  int y = bx / 5, xw = bx - y * 5;
  bool yeven = (y & 1) == 0;
  if (STATS) {
    #pragma unroll
    for (int mt = 0; mt < 4; ++mt) {
      #pragma unroll
      for (int q = 0; q < 16; ++q) {
        int r = mt * 32 + (q & 3) + 8 * (q >> 2) + 4 * hgrp;
        float s = scale_s[r] * (1.0f / (1.0f + expf(-acc[mt][q])));
        bool bb = s > 0.45f;
        unsigned long long bm = __ballot(bb);
        unsigned int hbits = (unsigned int)(bm >> (hgrp * 32));
        float ssum = bb ? s : 0.0f;
        #pragma unroll
        for (int off = 1; off <= 16; off <<= 1) ssum += __shfl_xor(ssum, off);
        if ((lane & 31) == 0) {
          red_s[0][r][w] = (float)__popc(hbits);
          red_s[1][r][w] = ssum;
        }
        if (yeven) {
          unsigned int ex = compact16(hbits);
          if ((lane & 31) == 0)
            atomicOr(&dsw_s[r][w >> 1], ex << ((w & 1) * 16));
        }
      }
    }
    __syncthreads();
    float* part = (float*)(ws + WS_PART);
    unsigned int* ds32 = (unsigned int*)(ws + WS_DS);
    int r = tid & 127, st = tid >> 7;
    part[bx * 256 + st * 128 + r] =
        red_s[st][r][0] + red_s[st][r][1] + red_s[st][r][2] + red_s[st][r][3];
    if (yeven) {
      int rr = tid >> 1, wd = tid & 1;
      ds32[rr * DSW + (y >> 1) * 10 + xw * 2 + wd] = dsw_s[rr][wd];
    }
  } else {
    #pragma unroll
    for (int mt = 0; mt < 4; ++mt) {
      #pragma unroll
      for (int q = 0; q < 16; ++q) {
        int r = mt * 32 + (q & 3) + 8 * (q >> 2) + 4 * hgrp;
        if (r < KCAND) {
          float o = scale_s[r] * (1.0f / (1.0f + expf(-acc[mt][q])));
          out[(size_t)r * NPIX + px] = o;
        }
      }
    }
  }
}

// ============ kernel 4: deterministic f64 reduce of per-block stat partials ============
__global__ __launch_bounds__(256) void stats_reduce_kernel(char* ws) {
  const float* part = (const float*)(ws + WS_PART);
  double* cntd  = (double*)(ws + WS_CNT);
  double* ssumd = (double*)(ws + WS_SSUM);
  __shared__ double cs_[256], ss_[256];
  int tid = threadIdx.x;
  int r = blockIdx.x;
  double c = 0.0, s = 0.0;
  for (int b = tid; b < NBLK; b += 256) {
    c += (double)part[b * 256 + r];
    s += (double)part[b * 256 + RPAD + r];
  }
  cs_[tid] = c; ss_[tid] = s;
  __syncthreads();
  for (int o = 128; o >= 1; o >>= 1) {
    if (tid < o) { cs_[tid] += cs_[tid + o]; ss_[tid] += ss_[tid + o]; }
    __syncthreads();
  }
  if (tid == 0) { cntd[r] = cs_[0]; ssumd[r] = ss_[0]; }
}

// ============ kernel 5: pairwise mask intersections (popcount over bitpacked ds) ============
__global__ __launch_bounds__(256) void inter_kernel(char* ws) {
  int i = blockIdx.y, j = blockIdx.x;
  if (j < i) return;
  const unsigned int* ds32 = (const unsigned int*)(ws + WS_DS);
  float* inter = (float*)(ws + WS_INTER);
  const unsigned int* a = ds32 + i * DSW;
  const unsigned int* b = ds32 + j * DSW;
  int s = 0;
  for (int w = threadIdx.x; w < DSW; w += 256) s += __popc(a[w] & b[w]);
  #pragma unroll
  for (int off = 32; off >= 1; off >>= 1) s += __shfl_xor(s, off);
  __shared__ int red[4];
  int lane = threadIdx.x & 63, wv = threadIdx.x >> 6;
  if (lane == 0) red[wv] = s;
  __syncthreads();
  if (threadIdx.x == 0) inter[i*KCAND + j] = (float)(red[0] + red[1] + red[2] + red[3]);
}

// ============ kernel 6: score/sort/matrix-NMS, small outputs, build A2/scale2 ============
__global__ __launch_bounds__(256) void nms_kernel(char* ws, float* __restrict__ out) {
  float* topv   = (float*)(ws + WS_TOPV);
  float* keepfg = (float*)(ws + WS_KEEPF);
  double* cntd  = (double*)(ws + WS_CNT);
  double* ssumd = (double*)(ws + WS_SSUM);
  float* inter  = (float*)(ws + WS_INTER);
  float* mnt    = (float*)(ws + WS_MNT);
  float* scale2 = (float*)(ws + WS_SCALE2);

  __shared__ float iou_s[KCAND*KCAND];   // 40 KB
  __shared__ float sc0[KCAND], sc_s[KCAND], keep_s[KCAND], s2_s[KCAND];
  __shared__ float comp_[KCAND], k2f_[KCAND];
  __shared__ int order_[KCAND];

  int tid = threadIdx.x;
  for (int r = tid; r < KCAND; r += 256) {
    double c = cntd[r], s = ssumd[r];
    float seg = (float)(s / fmax(c, 1.0));
    sc0[r] = topv[r] * seg;
  }
  __syncthreads();
  for (int i = tid; i < KCAND; i += 256) {
    float v = sc0[i]; int rk = 0;
    for (int j = 0; j < KCAND; ++j) {
      float u = sc0[j];
      rk += (int)((u > v) || (u == v && j < i));
    }
    order_[rk] = i;
  }
  __syncthreads();
  for (int i = tid; i < KCAND; i += 256) {
    int oi = order_[i];
    sc_s[i]   = sc0[oi];
    keep_s[i] = keepfg[oi];
    s2_s[i]   = inter[oi*KCAND + oi];
  }
  __syncthreads();
  for (int t = tid; t < KCAND*KCAND; t += 256) {
    int i = t / KCAND, j = t - i*KCAND;
    float v = 0.0f;
    if (i < j) {
      int oi = order_[i], oj = order_[j];
      int a = min(oi, oj), b = max(oi, oj);
      float iv = inter[a*KCAND + b];
      float un = s2_s[i] + s2_s[j] - iv;
      v = iv / fmaxf(un, 1e-6f);
    }
    iou_s[t] = v;
  }
  __syncthreads();
  for (int i = tid; i < KCAND; i += 256) {
    float m = 0.0f;
    for (int r = 0; r < KCAND; ++r) m = fmaxf(m, iou_s[r*KCAND + i]);
    comp_[i] = m;
  }
  __syncthreads();
  for (int j = tid; j < KCAND; j += 256) {
    float mv = 3.4e38f;
    for (int i = 0; i < KCAND; ++i) {
      float io = iou_s[i*KCAND + j];
      float cm = comp_[i];
      float ratio = expf(-2.0f*io*io) / expf(-2.0f*cm*cm);
      mv = fminf(mv, ratio);
    }
    float sc2 = sc_s[j] * mv;
    bool k2 = (sc2 >= 0.05f) && (keep_s[j] > 0.5f);
    float kf = k2 ? 1.0f : 0.0f;
    k2f_[j] = kf;
    out[MOUT + j] = sc2 * kf;                 // scores
    out[MOUT + KCAND + j] = 0.0f;             // labels
    out[MOUT + 2*KCAND + j] = kf;             // keep
  }
  __syncthreads();
  // permuted split A for gemm<false>
  prep_a(mnt, order_, ws + WS_APREP2, tid);
  for (int r = tid; r < RPAD; r += 256) scale2[r] = (r < KCAND) ? k2f_[r] : 0.0f;
}

extern "C" void kernel_launch(void* const* d_in, const int* in_sizes, int n_in,
                              void* d_out, int out_size, void* d_ws, size_t ws_size,
                              hipStream_t stream) {
  const float* pred = (const float*)d_in[0];
  const float* emb  = (const float*)d_in[1];
  const float* enc  = (const float*)d_in[2];
  float* out = (float*)d_out;
  char* ws = (char*)d_ws;

  topk_kernel<<<dim3(1), dim3(256), 0, stream>>>(pred, ws);
  fuse_kernel<<<dim3(1), dim3(256), 0, stream>>>(emb, ws);
  gemm_kernel<true><<<dim3(NBLK), dim3(256), 0, stream>>>(enc, ws, out);
  stats_reduce_kernel<<<dim3(RPAD), dim3(256), 0, stream>>>(ws);
  inter_kernel<<<dim3(100, 100), dim3(256), 0, stream>>>(ws);
  nms_kernel<<<dim3(1), dim3(256), 0, stream>>>(ws, out);
  gemm_kernel<false><<<dim3(NBLK), dim3(256), 0, stream>>>(enc, ws, out);
}